// Round 7
// baseline (1940.120 us; speedup 1.0000x reference)
//
#include <hip/hip_runtime.h>
#include <stdint.h>

// Problem constants
#define B_SZ 32
#define SEQ  512
#define DIM  768
#define NH   12
#define HD   64
#define ROWS (B_SZ*SEQ)   // 16384

typedef __attribute__((ext_vector_type(4))) float f32x4;
typedef __attribute__((ext_vector_type(8))) _Float16 half8;

// async global->LDS, 16B per lane; LDS dest = wave-uniform base + lane*16
#define GLOAD_LDS16(gaddr, laddr) \
  __builtin_amdgcn_global_load_lds((const __attribute__((address_space(1))) void*)(gaddr), \
                                   (__attribute__((address_space(3))) void*)(laddr), 16, 0, 0)

__device__ __forceinline__ unsigned short h2u(_Float16 h){
  union { _Float16 h; unsigned short u; } c; c.h = h; return c.u;
}
__device__ __forceinline__ unsigned short f2hu(float f){
  return h2u((_Float16)f);
}

// ---------------- prep kernels ----------------
__global__ void k_split(const float* __restrict__ x,
                        unsigned short* __restrict__ xh,
                        unsigned short* __restrict__ xl, int n4){
  int i = blockIdx.x * 256 + threadIdx.x;
  if (i >= n4) return;
  float4 v = ((const float4*)x)[i];
  ushort4 h, l;
  _Float16 t;
  t = (_Float16)v.x; h.x = h2u(t); l.x = f2hu(v.x - (float)t);
  t = (_Float16)v.y; h.y = h2u(t); l.y = f2hu(v.y - (float)t);
  t = (_Float16)v.z; h.z = h2u(t); l.z = f2hu(v.z - (float)t);
  t = (_Float16)v.w; h.w = h2u(t); l.w = f2hu(v.w - (float)t);
  ((ushort4*)xh)[i] = h;
  ((ushort4*)xl)[i] = l;
}

// QT[h][e][d] = split(Q[h][d][e]) — LDS-tiled transpose, both sides coalesced
__global__ __launch_bounds__(256) void k_transQ(const float* __restrict__ Q,
                         unsigned short* __restrict__ qth,
                         unsigned short* __restrict__ qtl){
  __shared__ float tile[32][33];
  int h = blockIdx.z;
  int d0 = blockIdx.x * 32;
  int e0 = blockIdx.y * 32;
  int tx = threadIdx.x & 31, ty = threadIdx.x >> 5;  // 32 x 8
  const float* Qh = Q + (size_t)h * DIM * DIM;
  for (int i = 0; i < 4; ++i)
    tile[ty + i*8][tx] = Qh[(size_t)(d0 + ty + i*8) * DIM + e0 + tx];
  __syncthreads();
  for (int i = 0; i < 4; ++i){
    float v = tile[tx][ty + i*8];
    size_t o = ((size_t)h * DIM + e0 + ty + i*8) * DIM + d0 + tx;
    _Float16 hi = (_Float16)v;
    qth[o] = h2u(hi);
    qtl[o] = f2hu(v - (float)hi);
  }
}

// Vt[h][e][d] = fp16(V[h][d][e]) — LDS-tiled transpose
__global__ __launch_bounds__(256) void k_transV(const float* __restrict__ V,
                         unsigned short* __restrict__ vt16){
  __shared__ float tile[32][33];
  int h = blockIdx.z;
  int d0 = blockIdx.x * 32;
  int e0 = blockIdx.y * 32;
  int tx = threadIdx.x & 31, ty = threadIdx.x >> 5;
  const float* Vh = V + (size_t)h * DIM * HD;
  for (int i = 0; i < 4; ++i)
    tile[ty + i*8][tx] = Vh[(size_t)(d0 + ty + i*8) * HD + e0 + tx];
  __syncthreads();
  for (int i = 0; i < 4; ++i)
    vt16[((size_t)h * HD + e0 + ty + i*8) * DIM + d0 + tx] = f2hu(tile[tx][ty + i*8]);
}

// ---------------- xV GEMM (round-0 proven: fp16 single-pass, BK=32) ----------------
__global__ __launch_bounds__(256) void k_gemm_xv(
    const unsigned short* __restrict__ xh,
    const unsigned short* __restrict__ vt16,
    unsigned short* __restrict__ xvT){
  __shared__ __align__(16) unsigned short lA[128*32];
  __shared__ __align__(16) unsigned short lB[64*32];
  __shared__ __align__(16) unsigned short lOut[64*128];
  int t = threadIdx.x, w = t >> 6, l = t & 63;
  int lane16 = l & 15, quad = l >> 4;
  int b = blockIdx.y, h = blockIdx.z;
  int m0 = blockIdx.x * 128;
  const unsigned short* vth = vt16 + (size_t)h * HD * DIM;
  f32x4 acc[2][4];
  for (int i = 0; i < 2; ++i) for (int j = 0; j < 4; ++j)
    for (int z = 0; z < 4; ++z) acc[i][j][z] = 0.f;

  for (int kt = 0; kt < DIM/32; ++kt){
    int k0 = kt * 32;
    __syncthreads();
    for (int rep = 0; rep < 2; ++rep){
      int id = t + rep * 256;              // 0..511
      int row = id >> 2, ko = (id & 3) * 8;
      GLOAD_LDS16(&xh[((size_t)(b*SEQ + m0 + row))*DIM + k0 + ko],
                  &lA[(rep*256 + w*64) * 8]);
    }
    { int row = t >> 2, ko = (t & 3) * 8;  // 64x32
      GLOAD_LDS16(&vth[(size_t)row*DIM + k0 + ko], &lB[(w*64) * 8]); }
    __syncthreads();
    half8 a[2];
    for (int i = 0; i < 2; ++i)
      a[i] = *(const half8*)&lA[(w*32 + i*16 + lane16)*32 + quad*8];
    for (int j = 0; j < 4; ++j){
      half8 bb = *(const half8*)&lB[(j*16 + lane16)*32 + quad*8];
      for (int i = 0; i < 2; ++i)
        acc[i][j] = __builtin_amdgcn_mfma_f32_16x16x32_f16(a[i], bb, acc[i][j], 0, 0, 0);
    }
  }
  __syncthreads();
  for (int i = 0; i < 2; ++i) for (int j = 0; j < 4; ++j) for (int r = 0; r < 4; ++r){
    int col = j*16 + lane16;
    int n  = w*32 + i*16 + quad*4 + r;
    lOut[col*128 + n] = f2hu(acc[i][j][r]);
  }
  __syncthreads();
  for (int rep = 0; rep < 4; ++rep){
    int id = t + rep*256;                  // 0..1023 int4s
    int e = id >> 4, no = (id & 15) * 8;
    *(int4*)&xvT[((size_t)(b*NH + h)*HD + e)*SEQ + m0 + no] = *(const int4*)&lOut[e*128 + no];
  }
}

// ---------------- q projection (r3-proven body + XCD-aware Mtile swizzle, r6) ----------------
__global__ __launch_bounds__(256, 2) void k_gemm_q(
    const unsigned short* __restrict__ xh, const unsigned short* __restrict__ xl,
    const unsigned short* __restrict__ bth, const unsigned short* __restrict__ btl,
    unsigned short* __restrict__ qh, unsigned short* __restrict__ ql, int ncols){
  __shared__ __align__(16) unsigned short lA[2][128*64];   // [hl] 32 KB
  __shared__ __align__(16) unsigned short lB[2][128*64];   // [hl] 32 KB
  int t = threadIdx.x, w = t >> 6, l = t & 63;
  int lane16 = l & 15, quad = l >> 4;
  // bijective XCD swizzle: n = y*128 + x (x fastest = dispatch order), xcd = n%8
  int nlin = blockIdx.y * gridDim.x + blockIdx.x;
  int xcd = nlin & 7, jj = nlin >> 3;
  int ntc = gridDim.y;                       // N-tile count (6*HC)
  int m0 = (xcd * 16 + jj / ntc) * 128;      // jj/ntc in [0,16)
  int n0 = (jj % ntc) * 128;
  int wr = (w >> 1) * 64, wc = (w & 1) * 64;
  f32x4 acc[4][4];
  for (int i = 0; i < 4; ++i) for (int j = 0; j < 4; ++j)
    for (int z = 0; z < 4; ++z) acc[i][j][z] = 0.f;

  for (int kt = 0; kt < DIM/64; ++kt){
    int k0 = kt * 64;
    __syncthreads();                       // previous compute's LDS reads done
    for (int rep = 0; rep < 4; ++rep){
      int id = t + rep * 256;              // 0..1023 (row, chunk)
      int row = id >> 3;
      int gc  = (id & 7) ^ (row & 7);      // fetch swizzled chunk into linear slot
      int lb  = (rep*256 + w*64) * 8;
      size_t gA = (size_t)(m0+row)*DIM + k0 + gc*8;
      size_t gB = (size_t)(n0+row)*DIM + k0 + gc*8;
      GLOAD_LDS16(&xh [gA], &lA[0][lb]);
      GLOAD_LDS16(&xl [gA], &lA[1][lb]);
      GLOAD_LDS16(&bth[gB], &lB[0][lb]);
      GLOAD_LDS16(&btl[gB], &lB[1][lb]);
    }
    __syncthreads();                       // drain staging
    for (int ks = 0; ks < 2; ++ks){
      int sw = ((ks*4 + quad) ^ (lane16 & 7)) * 8;   // swizzled chunk offset
      half8 aH[4], aL[4];
      for (int i = 0; i < 4; ++i){
        int r = wr + i*16 + lane16;
        aH[i] = *(const half8*)&lA[0][r*64 + sw];
        aL[i] = *(const half8*)&lA[1][r*64 + sw];
      }
      for (int j = 0; j < 4; ++j){
        int c = wc + j*16 + lane16;
        half8 bH = *(const half8*)&lB[0][c*64 + sw];
        half8 bL = *(const half8*)&lB[1][c*64 + sw];
        for (int i = 0; i < 4; ++i){
          acc[i][j] = __builtin_amdgcn_mfma_f32_16x16x32_f16(aL[i], bH, acc[i][j], 0, 0, 0);
          acc[i][j] = __builtin_amdgcn_mfma_f32_16x16x32_f16(aH[i], bL, acc[i][j], 0, 0, 0);
          acc[i][j] = __builtin_amdgcn_mfma_f32_16x16x32_f16(aH[i], bH, acc[i][j], 0, 0, 0);
        }
      }
    }
  }
  for (int i = 0; i < 4; ++i) for (int j = 0; j < 4; ++j) for (int r = 0; r < 4; ++r){
    int row = m0 + wr + i*16 + quad*4 + r;
    int col = n0 + wc + j*16 + lane16;
    float v = acc[i][j][r];
    _Float16 hh = (_Float16)v;
    size_t o = (size_t)row*ncols + col;
    qh[o] = h2u(hh);
    ql[o] = f2hu(v - (float)hh);
  }
}

// ---------------- fused attention: 2 blocks/CU, direct-output PV ----------------
// grid (8*hc, 32), b-grouped XCD swizzle (r6). block 512 (8 waves).
// LDS (72 KB + 2.5 KB stat -> 2 blocks/CU; r6 was 146.5 KB -> 1 block/CU, the
// m114 drain-hiding mechanism unavailable -> MfmaUtil 28% vs gemm_q's 40%):
//   keys [512 rows][64 shorts hi|lo interleaved, XOR-8 slots] @0      (64 KB)
//   q    [64 rows][64 shorts interleaved, XOR-8]              @32768  ( 8 KB)
//   P    [64 rows][512 keys fp16, key^((row&7)<<3) swizzle]   @0 alias (64 KB)
// Phase 1: single-buffered 2-barrier lockstep (gemm_q's proven shape; dbuf was
// the 1-block/CU cause). Phase 3 PV re-decomposed BY OUTPUT: wave w owns rows
// [(w&1)*32,+32) x e-cols [(w>>1)*16,+16), sums ALL 512 keys -> no cross-wave
// reduction (kills the 128 KB red buffer + 384 KB LDS round-trip); xv read
// directly from global (L2-hot on this XCD via b-grouping).
__global__ __launch_bounds__(512, 4) void k_attn(
    const unsigned short* __restrict__ qh, const unsigned short* __restrict__ ql,
    const unsigned short* __restrict__ xh, const unsigned short* __restrict__ xl,
    const unsigned short* __restrict__ xvT,
    float* __restrict__ out, int h0, int hc){
  __shared__ __align__(16) unsigned short lsh[36864];   // 72 KB
  __shared__ float lStat[8*64 + 64 + 64];               // 2.5 KB
  const int QB = 32768;

  int t = threadIdx.x, w = t >> 6, l = t & 63;
  int lane16 = l & 15, quad = l >> 4;
  // bijective XCD swizzle: XCD k owns batches [4k,4k+4)
  int nlin = blockIdx.y * gridDim.x + blockIdx.x;
  int xcd = nlin & 7, jj = nlin >> 3;
  int cpb = 8 * hc;
  int b = xcd * (B_SZ/8) + jj / cpb;
  int combo = jj % cpb;
  int hIdx = combo % hc, nt = combo / hc;
  int h = h0 + hIdx;
  int qstride = hc * DIM;
  size_t qoff = (size_t)hIdx * DIM;
  int n0 = nt * 64;
  size_t rowbase = (size_t)b * SEQ;
  const size_t dQ = (size_t)(ql - qh);      // hi->lo element offsets (uniform)
  const size_t dX = (size_t)(xl - xh);

  f32x4 accS[4][4];   // 4 q-row strips x 4 key strips (64 keys/wave)
  for (int i = 0; i < 4; ++i) for (int j = 0; j < 4; ++j)
    for (int z = 0; z < 4; ++z) accS[i][j][z] = 0.f;

  auto stage = [&](int kt){
    int k0 = kt * 32;
    { // q: 64 rows x 8 slots = 512 chunks, 1 per thread
      int row = t >> 3, s = t & 7, c = s ^ (row & 7);
      size_t hilo = (size_t)(c >> 2);
      GLOAD_LDS16(&qh[(rowbase + n0 + row)*qstride + qoff + k0 + (c & 3)*8 + hilo*dQ],
                  &lsh[QB + t*8]);
    }
    for (int rep = 0; rep < 8; ++rep){      // keys: 512 rows x 8 slots = 4096 chunks
      int id = t + rep * 512;
      int row = id >> 3, s = id & 7, c = s ^ (row & 7);
      size_t hilo = (size_t)(c >> 2);
      GLOAD_LDS16(&xh[(rowbase + row)*DIM + k0 + (c & 3)*8 + hilo*dX],
                  &lsh[id*8]);
    }
  };

  // ---- Phase 1: scores, single-buffered lockstep (2 blocks/CU hide drains) ----
  for (int kt = 0; kt < DIM/32; ++kt){
    __syncthreads();                 // previous compute's LDS reads done
    stage(kt);
    __syncthreads();                 // drain staging
    half8 aH[4], aL[4];
    for (int i = 0; i < 4; ++i){
      int r = i*16 + lane16;
      aH[i] = *(const half8*)&lsh[QB + r*64 + (( quad    ^ (r & 7))*8)];
      aL[i] = *(const half8*)&lsh[QB + r*64 + (((quad+4) ^ (r & 7))*8)];
    }
    for (int j = 0; j < 4; ++j){
      int c = w*64 + j*16 + lane16;
      half8 bH = *(const half8*)&lsh[c*64 + (( quad    ^ (c & 7))*8)];
      half8 bL = *(const half8*)&lsh[c*64 + (((quad+4) ^ (c & 7))*8)];
      for (int i = 0; i < 4; ++i){
        accS[i][j] = __builtin_amdgcn_mfma_f32_16x16x32_f16(aL[i], bH, accS[i][j], 0, 0, 0);
        accS[i][j] = __builtin_amdgcn_mfma_f32_16x16x32_f16(aH[i], bL, accS[i][j], 0, 0, 0);
        accS[i][j] = __builtin_amdgcn_mfma_f32_16x16x32_f16(aH[i], bH, accS[i][j], 0, 0, 0);
      }
    }
  }
  __syncthreads();   // keys/q LDS dead; P may alias after this point

  // ---- Phase 2: softmax ----
  float rmx[4][4];
  for (int i = 0; i < 4; ++i) for (int r = 0; r < 4; ++r){
    float m = accS[i][0][r];
    for (int j = 1; j < 4; ++j) m = fmaxf(m, accS[i][j][r]);
    for (int d = 1; d < 16; d <<= 1) m = fmaxf(m, __shfl_xor(m, d, 64));
    rmx[i][r] = m;
  }
  if (lane16 == 0)
    for (int i = 0; i < 4; ++i) for (int r = 0; r < 4; ++r)
      lStat[w*64 + i*16 + quad*4 + r] = rmx[i][r];
  __syncthreads();
  if (t < 64){
    float m = lStat[t];
    for (int ww = 1; ww < 8; ++ww) m = fmaxf(m, lStat[ww*64 + t]);
    lStat[512 + t] = m;
  }
  __syncthreads();
  float rsum[4][4];
  for (int i = 0; i < 4; ++i) for (int r = 0; r < 4; ++r){
    float g = lStat[512 + i*16 + quad*4 + r];
    float s = 0.f;
    int row = i*16 + quad*4 + r;
    int sw = (row & 7) << 3;
    for (int j = 0; j < 4; ++j){
      float p = __expf(accS[i][j][r] - g);
      s += p;
      int key = w*64 + j*16 + lane16;
      lsh[row*512 + (key ^ sw)] = f2hu(p);   // P, key-chunk XOR swizzle
    }
    for (int d = 1; d < 16; d <<= 1) s += __shfl_xor(s, d, 64);
    rsum[i][r] = s;
  }
  if (lane16 == 0)
    for (int i = 0; i < 4; ++i) for (int r = 0; r < 4; ++r)
      lStat[w*64 + i*16 + quad*4 + r] = rsum[i][r];
  __syncthreads();
  if (t < 64){
    float s = lStat[t];
    for (int ww = 1; ww < 8; ++ww) s += lStat[ww*64 + t];
    lStat[576 + t] = s;
  }
  __syncthreads();   // P + sums visible to all waves

  // ---- Phase 3: PV by output tile; wave w: rows [(w&1)*32,+32) x e [(w>>1)*16,+16) ----
  int rh = (w & 1) * 32, e0 = (w >> 1) * 16;
  f32x4 accO[2];
  for (int i = 0; i < 2; ++i) for (int z = 0; z < 4; ++z) accO[i][z] = 0.f;
  const unsigned short* xvp = xvT + ((size_t)(b*NH + h)*HD + e0 + lane16)*SEQ;
  for (int ks = 0; ks < 16; ++ks){
    int kb = ks*32;
    half8 bV = *(const half8*)&xvp[kb + quad*8];       // global, L2-hot
    for (int i = 0; i < 2; ++i){
      int row = rh + i*16 + lane16;
      half8 aP = *(const half8*)&lsh[row*512 + ((kb + quad*8) ^ ((row & 7) << 3))];
      accO[i] = __builtin_amdgcn_mfma_f32_16x16x32_f16(aP, bV, accO[i], 0, 0, 0);
    }
  }
  for (int i = 0; i < 2; ++i) for (int z = 0; z < 4; ++z){
    int row = rh + i*16 + quad*4 + z;
    out[(rowbase + n0 + row)*DIM + h*HD + e0 + lane16] = accO[i][z] / lStat[576 + row];
  }
}

// ---------------- launcher ----------------
extern "C" void kernel_launch(void* const* d_in, const int* in_sizes, int n_in,
                              void* d_out, int out_size, void* d_ws, size_t ws_size,
                              hipStream_t stream){
  const float* x = (const float*)d_in[0];
  const float* Q = (const float*)d_in[1];
  const float* V = (const float*)d_in[2];
  float* out = (float*)d_out;

  char* ws = (char*)d_ws;
  size_t off = 0;
  auto alloc = [&](size_t bytes) -> void* {
    void* p = ws + off;
    off += (bytes + 255) & ~(size_t)255;
    return p;
  };
  // NOTE: hi/lo pairs must stay contiguous (xl = xh + ROWS*DIM etc.) — the
  // staging code relies on constant hi->lo element offsets.
  unsigned short* xh  = (unsigned short*)alloc((size_t)ROWS*DIM*2);       // 25.2 MB
  unsigned short* xl  = (unsigned short*)alloc((size_t)ROWS*DIM*2);       // 25.2 MB
  unsigned short* qth = (unsigned short*)alloc((size_t)NH*DIM*DIM*2);     // 14.2 MB
  unsigned short* qtl = (unsigned short*)alloc((size_t)NH*DIM*DIM*2);     // 14.2 MB
  unsigned short* vt  = (unsigned short*)alloc((size_t)NH*HD*DIM*2);      //  1.2 MB
  unsigned short* xvT = (unsigned short*)alloc((size_t)B_SZ*NH*HD*SEQ*2); // 25.2 MB
  // fixed total ~105 MB

  // choose largest head-chunk whose q hi+lo buffers fit the workspace
  const int hcands[6] = {12, 6, 4, 3, 2, 1};
  int HC = 1;
  for (int i = 0; i < 6; ++i){
    size_t qb_bytes = ((size_t)ROWS * hcands[i] * DIM * 2 + 255) & ~(size_t)255;
    if (off + 2*qb_bytes <= ws_size){ HC = hcands[i]; break; }
  }
  unsigned short* qbh = (unsigned short*)alloc((size_t)ROWS*HC*DIM*2);
  unsigned short* qbl = (unsigned short*)alloc((size_t)ROWS*HC*DIM*2);

  int n4 = ROWS*DIM/4;
  k_split<<<n4/256, 256, 0, stream>>>(x, xh, xl, n4);
  k_transQ<<<dim3(DIM/32, DIM/32, NH), 256, 0, stream>>>(Q, qth, qtl);
  k_transV<<<dim3(DIM/32, HD/32, NH), 256, 0, stream>>>(V, vt);
  k_gemm_xv<<<dim3(4, B_SZ, NH), 256, 0, stream>>>(xh, vt, xvT);

  for (int h0 = 0; h0 < NH; h0 += HC){
    k_gemm_q<<<dim3(ROWS/128, HC*DIM/128), 256, 0, stream>>>(
        xh, xl, qth + (size_t)h0*DIM*DIM, qtl + (size_t)h0*DIM*DIM,
        qbh, qbl, HC*DIM);
    k_attn<<<dim3(8*HC, B_SZ), 512, 0, stream>>>(
        qbh, qbl, xh, xl, xvT, out, h0, HC);
  }
}

// Round 8
// 1283.734 us; speedup vs baseline: 1.5113x; 1.5113x over previous
//
#include <hip/hip_runtime.h>
#include <stdint.h>

// Problem constants
#define B_SZ 32
#define SEQ  512
#define DIM  768
#define NH   12
#define HD   64
#define ROWS (B_SZ*SEQ)   // 16384

typedef __attribute__((ext_vector_type(4))) float f32x4;
typedef __attribute__((ext_vector_type(8))) _Float16 half8;

// async global->LDS, 16B per lane; LDS dest = wave-uniform base + lane*16
#define GLOAD_LDS16(gaddr, laddr) \
  __builtin_amdgcn_global_load_lds((const __attribute__((address_space(1))) void*)(gaddr), \
                                   (__attribute__((address_space(3))) void*)(laddr), 16, 0, 0)

__device__ __forceinline__ unsigned short h2u(_Float16 h){
  union { _Float16 h; unsigned short u; } c; c.h = h; return c.u;
}
__device__ __forceinline__ unsigned short f2hu(float f){
  return h2u((_Float16)f);
}

// ---------------- prep kernels ----------------
__global__ void k_split(const float* __restrict__ x,
                        unsigned short* __restrict__ xh,
                        unsigned short* __restrict__ xl, int n4){
  int i = blockIdx.x * 256 + threadIdx.x;
  if (i >= n4) return;
  float4 v = ((const float4*)x)[i];
  ushort4 h, l;
  _Float16 t;
  t = (_Float16)v.x; h.x = h2u(t); l.x = f2hu(v.x - (float)t);
  t = (_Float16)v.y; h.y = h2u(t); l.y = f2hu(v.y - (float)t);
  t = (_Float16)v.z; h.z = h2u(t); l.z = f2hu(v.z - (float)t);
  t = (_Float16)v.w; h.w = h2u(t); l.w = f2hu(v.w - (float)t);
  ((ushort4*)xh)[i] = h;
  ((ushort4*)xl)[i] = l;
}

// QT[h][e][d] = split(Q[h][d][e]) — LDS-tiled transpose, both sides coalesced
__global__ __launch_bounds__(256) void k_transQ(const float* __restrict__ Q,
                         unsigned short* __restrict__ qth,
                         unsigned short* __restrict__ qtl){
  __shared__ float tile[32][33];
  int h = blockIdx.z;
  int d0 = blockIdx.x * 32;
  int e0 = blockIdx.y * 32;
  int tx = threadIdx.x & 31, ty = threadIdx.x >> 5;  // 32 x 8
  const float* Qh = Q + (size_t)h * DIM * DIM;
  for (int i = 0; i < 4; ++i)
    tile[ty + i*8][tx] = Qh[(size_t)(d0 + ty + i*8) * DIM + e0 + tx];
  __syncthreads();
  for (int i = 0; i < 4; ++i){
    float v = tile[tx][ty + i*8];
    size_t o = ((size_t)h * DIM + e0 + ty + i*8) * DIM + d0 + tx;
    _Float16 hi = (_Float16)v;
    qth[o] = h2u(hi);
    qtl[o] = f2hu(v - (float)hi);
  }
}

// Vt[h][e][d] = fp16(V[h][d][e]) — LDS-tiled transpose
__global__ __launch_bounds__(256) void k_transV(const float* __restrict__ V,
                         unsigned short* __restrict__ vt16){
  __shared__ float tile[32][33];
  int h = blockIdx.z;
  int d0 = blockIdx.x * 32;
  int e0 = blockIdx.y * 32;
  int tx = threadIdx.x & 31, ty = threadIdx.x >> 5;
  const float* Vh = V + (size_t)h * DIM * HD;
  for (int i = 0; i < 4; ++i)
    tile[ty + i*8][tx] = Vh[(size_t)(d0 + ty + i*8) * HD + e0 + tx];
  __syncthreads();
  for (int i = 0; i < 4; ++i)
    vt16[((size_t)h * HD + e0 + ty + i*8) * DIM + d0 + tx] = f2hu(tile[tx][ty + i*8]);
}

// ---------------- xV GEMM (round-0 proven: fp16 single-pass, BK=32) ----------------
__global__ __launch_bounds__(256) void k_gemm_xv(
    const unsigned short* __restrict__ xh,
    const unsigned short* __restrict__ vt16,
    unsigned short* __restrict__ xvT){
  __shared__ __align__(16) unsigned short lA[128*32];
  __shared__ __align__(16) unsigned short lB[64*32];
  __shared__ __align__(16) unsigned short lOut[64*128];
  int t = threadIdx.x, w = t >> 6, l = t & 63;
  int lane16 = l & 15, quad = l >> 4;
  int b = blockIdx.y, h = blockIdx.z;
  int m0 = blockIdx.x * 128;
  const unsigned short* vth = vt16 + (size_t)h * HD * DIM;
  f32x4 acc[2][4];
  for (int i = 0; i < 2; ++i) for (int j = 0; j < 4; ++j)
    for (int z = 0; z < 4; ++z) acc[i][j][z] = 0.f;

  for (int kt = 0; kt < DIM/32; ++kt){
    int k0 = kt * 32;
    __syncthreads();
    for (int rep = 0; rep < 2; ++rep){
      int id = t + rep * 256;              // 0..511
      int row = id >> 2, ko = (id & 3) * 8;
      GLOAD_LDS16(&xh[((size_t)(b*SEQ + m0 + row))*DIM + k0 + ko],
                  &lA[(rep*256 + w*64) * 8]);
    }
    { int row = t >> 2, ko = (t & 3) * 8;  // 64x32
      GLOAD_LDS16(&vth[(size_t)row*DIM + k0 + ko], &lB[(w*64) * 8]); }
    __syncthreads();
    half8 a[2];
    for (int i = 0; i < 2; ++i)
      a[i] = *(const half8*)&lA[(w*32 + i*16 + lane16)*32 + quad*8];
    for (int j = 0; j < 4; ++j){
      half8 bb = *(const half8*)&lB[(j*16 + lane16)*32 + quad*8];
      for (int i = 0; i < 2; ++i)
        acc[i][j] = __builtin_amdgcn_mfma_f32_16x16x32_f16(a[i], bb, acc[i][j], 0, 0, 0);
    }
  }
  __syncthreads();
  for (int i = 0; i < 2; ++i) for (int j = 0; j < 4; ++j) for (int r = 0; r < 4; ++r){
    int col = j*16 + lane16;
    int n  = w*32 + i*16 + quad*4 + r;
    lOut[col*128 + n] = f2hu(acc[i][j][r]);
  }
  __syncthreads();
  for (int rep = 0; rep < 4; ++rep){
    int id = t + rep*256;                  // 0..1023 int4s
    int e = id >> 4, no = (id & 15) * 8;
    *(int4*)&xvT[((size_t)(b*NH + h)*HD + e)*SEQ + m0 + no] = *(const int4*)&lOut[e*128 + no];
  }
}

// ---------------- q projection (r6-proven: 2-barrier BK=64 + XCD Mtile swizzle) ----------------
__global__ __launch_bounds__(256, 2) void k_gemm_q(
    const unsigned short* __restrict__ xh, const unsigned short* __restrict__ xl,
    const unsigned short* __restrict__ bth, const unsigned short* __restrict__ btl,
    unsigned short* __restrict__ qh, unsigned short* __restrict__ ql, int ncols){
  __shared__ __align__(16) unsigned short lA[2][128*64];   // [hl] 32 KB
  __shared__ __align__(16) unsigned short lB[2][128*64];   // [hl] 32 KB
  int t = threadIdx.x, w = t >> 6, l = t & 63;
  int lane16 = l & 15, quad = l >> 4;
  // bijective XCD swizzle: XCD k owns Mtiles [16k,16k+16) sweeping all Ntiles
  int nlin = blockIdx.y * gridDim.x + blockIdx.x;
  int xcd = nlin & 7, jj = nlin >> 3;
  int ntc = gridDim.y;
  int m0 = (xcd * 16 + jj / ntc) * 128;
  int n0 = (jj % ntc) * 128;
  int wr = (w >> 1) * 64, wc = (w & 1) * 64;
  f32x4 acc[4][4];
  for (int i = 0; i < 4; ++i) for (int j = 0; j < 4; ++j)
    for (int z = 0; z < 4; ++z) acc[i][j][z] = 0.f;

  for (int kt = 0; kt < DIM/64; ++kt){
    int k0 = kt * 64;
    __syncthreads();
    for (int rep = 0; rep < 4; ++rep){
      int id = t + rep * 256;
      int row = id >> 3;
      int gc  = (id & 7) ^ (row & 7);
      int lb  = (rep*256 + w*64) * 8;
      size_t gA = (size_t)(m0+row)*DIM + k0 + gc*8;
      size_t gB = (size_t)(n0+row)*DIM + k0 + gc*8;
      GLOAD_LDS16(&xh [gA], &lA[0][lb]);
      GLOAD_LDS16(&xl [gA], &lA[1][lb]);
      GLOAD_LDS16(&bth[gB], &lB[0][lb]);
      GLOAD_LDS16(&btl[gB], &lB[1][lb]);
    }
    __syncthreads();
    for (int ks = 0; ks < 2; ++ks){
      int sw = ((ks*4 + quad) ^ (lane16 & 7)) * 8;
      half8 aH[4], aL[4];
      for (int i = 0; i < 4; ++i){
        int r = wr + i*16 + lane16;
        aH[i] = *(const half8*)&lA[0][r*64 + sw];
        aL[i] = *(const half8*)&lA[1][r*64 + sw];
      }
      for (int j = 0; j < 4; ++j){
        int c = wc + j*16 + lane16;
        half8 bH = *(const half8*)&lB[0][c*64 + sw];
        half8 bL = *(const half8*)&lB[1][c*64 + sw];
        for (int i = 0; i < 4; ++i){
          acc[i][j] = __builtin_amdgcn_mfma_f32_16x16x32_f16(aL[i], bH, acc[i][j], 0, 0, 0);
          acc[i][j] = __builtin_amdgcn_mfma_f32_16x16x32_f16(aH[i], bL, acc[i][j], 0, 0, 0);
          acc[i][j] = __builtin_amdgcn_mfma_f32_16x16x32_f16(aH[i], bH, acc[i][j], 0, 0, 0);
        }
      }
    }
  }
  for (int i = 0; i < 4; ++i) for (int j = 0; j < 4; ++j) for (int r = 0; r < 4; ++r){
    int row = m0 + wr + i*16 + quad*4 + r;
    int col = n0 + wc + j*16 + lane16;
    float v = acc[i][j][r];
    _Float16 hh = (_Float16)v;
    size_t o = (size_t)row*ncols + col;
    qh[o] = h2u(hh);
    ql[o] = f2hu(v - (float)hh);
  }
}

// ---------------- fused attention: HEAD-PAIR blocks (keys staged once per 2 heads) ----------------
// grid (8*(hc/2), 32), b-grouped XCD swizzle. block 512 (8 waves), 1 block/CU.
// Each block: batch b, q-rows [n0,n0+64), heads (2p, 2p+1) — keys (h-independent,
// 4096 DMA chunks/kt, the dominant staging cost per r6's pipe model) staged ONCE
// for both heads; MFMA per kt doubles to 96/wave -> staging amortized 2x.
// LDS lsh[73728] (144 KB, = r6 footprint): keys dbuf [bb*32768 + id*8] (128 KB);
// q single-buf [65536 + hh*4096 + t*8] (2 heads x 8 KB, 128B hi|lo XOR-8 rows).
// Loop: sync (keys(kt) drained, prev q reads done); stage_q(kt); sync (drains q
// only - keys(kt+1) not yet issued); stage_keys(kt+1) -> prefetch rides under
// compute. All plain __syncthreads, no counted-vmcnt races.
// Phases 2/3 per head sequential = r6-proven code (P @0 stride 520, xv @34816,
// red float[32768] alias @0).
#define SEQP 520
__global__ __launch_bounds__(512, 2) void k_attn(
    const unsigned short* __restrict__ qh, const unsigned short* __restrict__ ql,
    const unsigned short* __restrict__ xh, const unsigned short* __restrict__ xl,
    const unsigned short* __restrict__ xvT,
    float* __restrict__ out, int h0, int hc){
  __shared__ __align__(16) unsigned short lsh[73728];   // 144 KB
  __shared__ float lStat[8*64 + 64 + 64];               // 2.5 KB

  int t = threadIdx.x, w = t >> 6, l = t & 63;
  int lane16 = l & 15, quad = l >> 4;
  // bijective XCD swizzle: XCD k owns batches [4k,4k+4)
  int nlin = blockIdx.y * gridDim.x + blockIdx.x;
  int xcd = nlin & 7, jj = nlin >> 3;
  int hp = hc >> 1;                         // head pairs per launch
  int cpb = 8 * hp;                         // combos per batch
  int b = xcd * (B_SZ/8) + jj / cpb;
  int combo = jj % cpb;
  int pIdx = combo % hp, nt = combo / hp;
  int qstride = hc * DIM;
  size_t qoff0 = (size_t)(2*pIdx) * DIM;    // head 2p cols; head 2p+1 = +DIM
  int n0 = nt * 64;
  size_t rowbase = (size_t)b * SEQ;
  const size_t dQ = (size_t)(ql - qh);
  const size_t dX = (size_t)(xl - xh);

  f32x4 accS0[4][4], accS1[4][4];           // per-head score accs (static idx)
  for (int i = 0; i < 4; ++i) for (int j = 0; j < 4; ++j)
    for (int z = 0; z < 4; ++z){ accS0[i][j][z] = 0.f; accS1[i][j][z] = 0.f; }

  auto stage_keys = [&](int kt){
    int k0 = kt * 32, kb = (kt & 1) * 32768;
    for (int rep = 0; rep < 8; ++rep){
      int id = t + rep * 512;
      int row = id >> 3, s = id & 7, c = s ^ (row & 7);
      size_t hilo = (size_t)(c >> 2);
      GLOAD_LDS16(&xh[(rowbase + row)*DIM + k0 + (c & 3)*8 + hilo*dX],
                  &lsh[kb + id*8]);
    }
  };
  auto stage_q = [&](int kt){
    int k0 = kt * 32;
    int row = t >> 3, s = t & 7, c = s ^ (row & 7);
    size_t hilo = (size_t)(c >> 2);
    size_t g = (rowbase + n0 + row)*(size_t)qstride + qoff0 + k0 + (c & 3)*8 + hilo*dQ;
    GLOAD_LDS16(&qh[g],       &lsh[65536 + t*8]);          // head 2p
    GLOAD_LDS16(&qh[g + DIM], &lsh[65536 + 4096 + t*8]);   // head 2p+1
  };

  // ---- Phase 1 ----
  stage_keys(0);
  for (int kt = 0; kt < DIM/32; ++kt){
    __syncthreads();                 // keys(kt) drained; prev q reads done
    stage_q(kt);
    __syncthreads();                 // q(kt) drained (keys(kt+1) not yet issued)
    if (kt + 1 < DIM/32) stage_keys(kt + 1);   // prefetch under compute
    int kb = (kt & 1) * 32768;
    // head 0 of pair
    {
      half8 aH[4], aL[4];
      #pragma unroll
      for (int i = 0; i < 4; ++i){
        int r = i*16 + lane16;
        aH[i] = *(const half8*)&lsh[65536 + r*64 + (( quad    ^ (r & 7))*8)];
        aL[i] = *(const half8*)&lsh[65536 + r*64 + (((quad+4) ^ (r & 7))*8)];
      }
      #pragma unroll
      for (int j = 0; j < 4; ++j){
        int c = w*64 + j*16 + lane16;
        half8 bH = *(const half8*)&lsh[kb + c*64 + (( quad    ^ (c & 7))*8)];
        half8 bL = *(const half8*)&lsh[kb + c*64 + (((quad+4) ^ (c & 7))*8)];
        #pragma unroll
        for (int i = 0; i < 4; ++i){
          accS0[i][j] = __builtin_amdgcn_mfma_f32_16x16x32_f16(aL[i], bH, accS0[i][j], 0, 0, 0);
          accS0[i][j] = __builtin_amdgcn_mfma_f32_16x16x32_f16(aH[i], bL, accS0[i][j], 0, 0, 0);
          accS0[i][j] = __builtin_amdgcn_mfma_f32_16x16x32_f16(aH[i], bH, accS0[i][j], 0, 0, 0);
        }
      }
    }
    // head 1 of pair (re-reads key frags; halves live q-frag registers)
    {
      half8 aH[4], aL[4];
      #pragma unroll
      for (int i = 0; i < 4; ++i){
        int r = i*16 + lane16;
        aH[i] = *(const half8*)&lsh[65536 + 4096 + r*64 + (( quad    ^ (r & 7))*8)];
        aL[i] = *(const half8*)&lsh[65536 + 4096 + r*64 + (((quad+4) ^ (r & 7))*8)];
      }
      #pragma unroll
      for (int j = 0; j < 4; ++j){
        int c = w*64 + j*16 + lane16;
        half8 bH = *(const half8*)&lsh[kb + c*64 + (( quad    ^ (c & 7))*8)];
        half8 bL = *(const half8*)&lsh[kb + c*64 + (((quad+4) ^ (c & 7))*8)];
        #pragma unroll
        for (int i = 0; i < 4; ++i){
          accS1[i][j] = __builtin_amdgcn_mfma_f32_16x16x32_f16(aL[i], bH, accS1[i][j], 0, 0, 0);
          accS1[i][j] = __builtin_amdgcn_mfma_f32_16x16x32_f16(aH[i], bL, accS1[i][j], 0, 0, 0);
          accS1[i][j] = __builtin_amdgcn_mfma_f32_16x16x32_f16(aH[i], bH, accS1[i][j], 0, 0, 0);
        }
      }
    }
  }
  __syncthreads();   // keys/q dead; P/xv/red may alias

  // ---- Phases 2+3 per head (r6-proven body) ----
  const int XVB = 34816;
  auto p23 = [&](f32x4 (&accS)[4][4], int myh){
    // stage xv rows (overlaps softmax VALU)
    for (int it = 0; it < 8; ++it){
      int e = it*8 + w;
      GLOAD_LDS16(&xvT[((size_t)(b*NH + myh)*HD + e)*SEQ + l*8], &lsh[XVB + e*SEQP]);
    }
    float rmx[4][4];
    #pragma unroll
    for (int i = 0; i < 4; ++i) for (int r = 0; r < 4; ++r){
      float m = accS[i][0][r];
      for (int j = 1; j < 4; ++j) m = fmaxf(m, accS[i][j][r]);
      for (int d = 1; d < 16; d <<= 1) m = fmaxf(m, __shfl_xor(m, d, 64));
      rmx[i][r] = m;
    }
    if (lane16 == 0)
      for (int i = 0; i < 4; ++i) for (int r = 0; r < 4; ++r)
        lStat[w*64 + i*16 + quad*4 + r] = rmx[i][r];
    __syncthreads();
    if (t < 64){
      float m = lStat[t];
      for (int ww = 1; ww < 8; ++ww) m = fmaxf(m, lStat[ww*64 + t]);
      lStat[512 + t] = m;
    }
    __syncthreads();
    float rsum[4][4];
    #pragma unroll
    for (int i = 0; i < 4; ++i) for (int r = 0; r < 4; ++r){
      float g = lStat[512 + i*16 + quad*4 + r];
      float s = 0.f;
      for (int j = 0; j < 4; ++j){
        float p = __expf(accS[i][j][r] - g);
        s += p;
        lsh[(i*16 + quad*4 + r)*SEQP + (w*64 + j*16 + lane16)] = f2hu(p);
      }
      for (int d = 1; d < 16; d <<= 1) s += __shfl_xor(s, d, 64);
      rsum[i][r] = s;
    }
    if (lane16 == 0)
      for (int i = 0; i < 4; ++i) for (int r = 0; r < 4; ++r)
        lStat[w*64 + i*16 + quad*4 + r] = rsum[i][r];
    __syncthreads();
    if (t < 64){
      float s = lStat[t];
      for (int ww = 1; ww < 8; ++ww) s += lStat[ww*64 + t];
      lStat[576 + t] = s;
    }
    __syncthreads();   // P + xv + sums visible (drains xv DMA)

    f32x4 accO[4][4];
    for (int i = 0; i < 4; ++i) for (int j = 0; j < 4; ++j)
      for (int z = 0; z < 4; ++z) accO[i][j][z] = 0.f;
    for (int ks = 0; ks < 2; ++ks){
      int kb = w*64 + ks*32;
      half8 aP[4];
      #pragma unroll
      for (int i = 0; i < 4; ++i)
        aP[i] = *(const half8*)&lsh[(i*16 + lane16)*SEQP + kb + quad*8];
      #pragma unroll
      for (int j = 0; j < 4; ++j){
        half8 bV = *(const half8*)&lsh[XVB + (j*16 + lane16)*SEQP + kb + quad*8];
        for (int i = 0; i < 4; ++i)
          accO[i][j] = __builtin_amdgcn_mfma_f32_16x16x32_f16(aP[i], bV, accO[i][j], 0, 0, 0);
      }
    }
    __syncthreads();   // all reads of P/xv done before red overwrite
    float* red = (float*)lsh;
    for (int i = 0; i < 4; ++i) for (int j = 0; j < 4; ++j) for (int r = 0; r < 4; ++r)
      red[w*4096 + (i*16 + quad*4 + r)*64 + (j*16 + lane16)] = accO[i][j][r];
    __syncthreads();
    for (int z = t; z < 4096; z += 512){
      int row = z >> 6, col = z & 63;
      float v = 0.f;
      for (int ww = 0; ww < 8; ++ww) v += red[ww*4096 + z];
      v /= lStat[576 + row];
      out[(rowbase + n0 + row)*DIM + myh*HD + col] = v;
    }
    __syncthreads();   // red/lStat reads done before next head reuses
  };

  p23(accS0, h0 + 2*pIdx);
  p23(accS1, h0 + 2*pIdx + 1);
}

// ---------------- launcher ----------------
extern "C" void kernel_launch(void* const* d_in, const int* in_sizes, int n_in,
                              void* d_out, int out_size, void* d_ws, size_t ws_size,
                              hipStream_t stream){
  const float* x = (const float*)d_in[0];
  const float* Q = (const float*)d_in[1];
  const float* V = (const float*)d_in[2];
  float* out = (float*)d_out;

  char* ws = (char*)d_ws;
  size_t off = 0;
  auto alloc = [&](size_t bytes) -> void* {
    void* p = ws + off;
    off += (bytes + 255) & ~(size_t)255;
    return p;
  };
  // NOTE: hi/lo pairs must stay contiguous (xl = xh + ROWS*DIM etc.)
  unsigned short* xh  = (unsigned short*)alloc((size_t)ROWS*DIM*2);       // 25.2 MB
  unsigned short* xl  = (unsigned short*)alloc((size_t)ROWS*DIM*2);       // 25.2 MB
  unsigned short* qth = (unsigned short*)alloc((size_t)NH*DIM*DIM*2);     // 14.2 MB
  unsigned short* qtl = (unsigned short*)alloc((size_t)NH*DIM*DIM*2);     // 14.2 MB
  unsigned short* vt  = (unsigned short*)alloc((size_t)NH*HD*DIM*2);      //  1.2 MB
  unsigned short* xvT = (unsigned short*)alloc((size_t)B_SZ*NH*HD*SEQ*2); // 25.2 MB
  // fixed total ~105 MB

  // largest EVEN head-chunk whose q hi+lo buffers fit (attn pairs heads)
  const int hcands[3] = {6, 4, 2};
  int HC = 2;
  for (int i = 0; i < 3; ++i){
    size_t qb_bytes = ((size_t)ROWS * hcands[i] * DIM * 2 + 255) & ~(size_t)255;
    if (off + 2*qb_bytes <= ws_size){ HC = hcands[i]; break; }
  }
  unsigned short* qbh = (unsigned short*)alloc((size_t)ROWS*HC*DIM*2);
  unsigned short* qbl = (unsigned short*)alloc((size_t)ROWS*HC*DIM*2);

  int n4 = ROWS*DIM/4;
  k_split<<<n4/256, 256, 0, stream>>>(x, xh, xl, n4);
  k_transQ<<<dim3(DIM/32, DIM/32, NH), 256, 0, stream>>>(Q, qth, qtl);
  k_transV<<<dim3(DIM/32, HD/32, NH), 256, 0, stream>>>(V, vt);
  k_gemm_xv<<<dim3(4, B_SZ, NH), 256, 0, stream>>>(xh, vt, xvT);

  for (int h0 = 0; h0 < NH; h0 += HC){
    k_gemm_q<<<dim3(ROWS/128, HC*DIM/128), 256, 0, stream>>>(
        xh, xl, qth + (size_t)h0*DIM*DIM, qtl + (size_t)h0*DIM*DIM,
        qbh, qbl, HC*DIM);
    k_attn<<<dim3(8*(HC/2), B_SZ), 512, 0, stream>>>(
        qbh, qbl, xh, xl, xvT, out, h0, HC);
  }
}